// Round 14
// baseline (4518.236 us; speedup 1.0000x reference)
//
#include <hip/hip_runtime.h>
#include <hip/hip_bf16.h>
#include <math.h>

#define BB 64
#define TT 64
#define INDIM 256
#define HH 512
#define NN 4096
#define MM 128
#define SS 32            // sweep slabs per batch
#define ROWS 128         // rows per sweep block = NN/SS
#define WC 544           // packed head-weight columns (512 + 12 + pad)
#define EPSF 1e-8f

__device__ __forceinline__ float fsig(float x){ return 1.f/(1.f+__expf(-x)); }
__device__ __forceinline__ float ftanh(float x){ return 1.f - 2.f/(__expf(2.f*x)+1.f); }
__device__ __forceinline__ float softplusf_(float x){ return (x>20.f)? x : log1pf(expf(x)); }

__device__ __forceinline__ void unpack2(unsigned u, float& lo, float& hi){
  lo = __uint_as_float(u << 16);
  hi = __uint_as_float(u & 0xffff0000u);
}
__device__ __forceinline__ unsigned packrn(float a, float b){
  __hip_bfloat162 p = __float22bfloat162_rn(make_float2(a,b));
  return *reinterpret_cast<unsigned*>(&p);
}

// ---------------- kCvt: fp32 mem0 -> bf16 mem (once) -----------------------
__global__ __launch_bounds__(256) void kCvt(const float* __restrict__ src,
                                            uint4* __restrict__ dst){
  const size_t i = (size_t)blockIdx.x*blockDim.x + threadIdx.x;
  const float4 f0 = *(const float4*)(src + i*8);
  const float4 f1 = *(const float4*)(src + i*8 + 4);
  uint4 q;
  q.x = packrn(f0.x, f0.y); q.y = packrn(f0.z, f0.w);
  q.z = packrn(f1.x, f1.y); q.w = packrn(f1.z, f1.w);
  dst[i] = q;
}

// ---------------- kInit (once) ---------------------------------------------
__global__ void kInit(float* wr, float* ww, float* headout){
  const int i = blockIdx.x*blockDim.x + threadIdx.x;
  if (i < BB*NN){ const float v = (i==0)? 1.f : 0.f; wr[i]=v; ww[i]=v; }
  if (i < BB*WC) headout[i]=0.f;   // h0=0 -> raw head outputs 0
}

// ---------------- kPack: concat head weights into Wall[512][544] (once) ----
__global__ __launch_bounds__(576) void kPack(
    const float* __restrict__ rWk, const float* __restrict__ wWk,
    const float* __restrict__ wWe, const float* __restrict__ wWa,
    const float* __restrict__ rWbeta, const float* __restrict__ rWg,
    const float* __restrict__ rWs, const float* __restrict__ rWgam,
    const float* __restrict__ wWbeta, const float* __restrict__ wWg,
    const float* __restrict__ wWs, const float* __restrict__ wWgam,
    float* __restrict__ Wall)
{
  const int j = blockIdx.x, c = threadIdx.x;
  if (c >= WC) return;
  float v = 0.f;
  if      (c < 128) v = rWk[(size_t)j*128 + c];
  else if (c < 256) v = wWk[(size_t)j*128 + c-128];
  else if (c < 384) v = wWe[(size_t)j*128 + c-256];
  else if (c < 512) v = wWa[(size_t)j*128 + c-384];
  else {
    const int cc = c - 512;
    switch (cc){
      case 0:  v = rWbeta[j]; break;
      case 1:  v = rWg[j];    break;
      case 2: case 3: case 4: v = rWs[(size_t)j*3 + cc-2]; break;
      case 5:  v = rWgam[j];  break;
      case 6:  v = wWbeta[j]; break;
      case 7:  v = wWg[j];    break;
      case 8: case 9: case 10: v = wWs[(size_t)j*3 + cc-8]; break;
      case 11: v = wWgam[j];  break;
      default: v = 0.f; break;
    }
  }
  Wall[(size_t)j*WC + c] = v;
}

// ---------------- kPre: xwx = bC + x@Wx, 16 bt-rows per block (once) -------
__global__ __launch_bounds__(512) void kPre(const float* __restrict__ x,
                                            const float* __restrict__ Wx,
                                            const float* __restrict__ bC,
                                            float* __restrict__ xwx){
  const int bt0 = blockIdx.x*16, t = threadIdx.x;
  __shared__ float xs[INDIM][16];
  for (int lin = t; lin < 16*INDIM; lin += 512){
    const int ii = lin & 255, r = lin >> 8;
    xs[ii][r] = x[(size_t)(bt0+r)*INDIM + ii];
  }
  __syncthreads();
  float accv[16];
  #pragma unroll
  for (int r=0;r<16;++r) accv[r]=0.f;
  for (int ii=0; ii<INDIM; ++ii){
    const float w = Wx[(size_t)ii*HH + t];
    const float4* xp = (const float4*)&xs[ii][0];
    const float4 x0=xp[0], x1=xp[1], x2=xp[2], x3=xp[3];
    accv[0]+=x0.x*w; accv[1]+=x0.y*w; accv[2]+=x0.z*w; accv[3]+=x0.w*w;
    accv[4]+=x1.x*w; accv[5]+=x1.y*w; accv[6]+=x1.z*w; accv[7]+=x1.w*w;
    accv[8]+=x2.x*w; accv[9]+=x2.y*w; accv[10]+=x2.z*w; accv[11]+=x2.w*w;
    accv[12]+=x3.x*w; accv[13]+=x3.y*w; accv[14]+=x3.z*w; accv[15]+=x3.w*w;
  }
  const float bc = bC[t];
  #pragma unroll
  for (int r=0;r<16;++r)
    xwx[(size_t)(bt0+r)*HH + t] = accv[r] + bc;
}

// ---------------- Kernel A: mem update + r partials + mnorm ----------------
// Per-lane predicated store: skip 16B chunks that round to identical bf16.
__global__ __launch_bounds__(256) void kA(
    const float* __restrict__ headout,
    const float* __restrict__ wrG, const float* __restrict__ wwG,
    uint4* __restrict__ mem, float* __restrict__ rpart, float* __restrict__ mnormG)
{
  const int b = blockIdx.y;
  const int n0 = blockIdx.x * ROWS;
  const int t = threadIdx.x;
  const int grp = t >> 4, lane = t & 15;
  const int m0 = lane * 8;
  const float* HO = headout + (size_t)b*WC;
  float ev[8], av[8];
  #pragma unroll
  for (int j=0;j<8;++j){
    ev[j] = fsig (HO[256 + m0 + j]);
    av[j] = ftanh(HO[384 + m0 + j]);
  }
  float wwv[8], wrv[8];
  #pragma unroll
  for (int rr=0; rr<8; ++rr){
    const int n = n0 + rr*16 + grp;
    wwv[rr] = wwG[b*NN+n];
    wrv[rr] = wrG[b*NN+n];
  }
  float racc[8];
  #pragma unroll
  for (int j=0;j<8;++j) racc[j]=0.f;
  __shared__ float lr[16][128];
  const size_t base4 = ((size_t)b*NN + n0)*(MM/8) + (size_t)grp*(MM/8) + lane;
  uint4 q = mem[base4];
  #pragma unroll
  for (int rr=0; rr<8; ++rr){
    uint4 qn;
    if (rr<7) qn = mem[base4 + (size_t)(rr+1)*16*(MM/8)];
    const int n = n0 + rr*16 + grp;
    float v[8];
    unpack2(q.x, v[0], v[1]); unpack2(q.y, v[2], v[3]);
    unpack2(q.z, v[4], v[5]); unpack2(q.w, v[6], v[7]);
    float sq = 0.f;
    const float w = wwv[rr], wr_ = wrv[rr];
    #pragma unroll
    for (int j=0;j<8;++j){
      v[j] = v[j]*(1.f - w*ev[j]) + w*av[j];
      racc[j] += wr_*v[j];
      sq += v[j]*v[j];
    }
    uint4 q2;
    q2.x = packrn(v[0],v[1]); q2.y = packrn(v[2],v[3]);
    q2.z = packrn(v[4],v[5]); q2.w = packrn(v[6],v[7]);
    const unsigned chg = (q2.x^q.x)|(q2.y^q.y)|(q2.z^q.z)|(q2.w^q.w);
    if (chg) mem[base4 + (size_t)rr*16*(MM/8)] = q2;   // exec-masked, per-lane
    #pragma unroll
    for (int msk=1; msk<16; msk<<=1) sq += __shfl_xor(sq, msk);
    if (lane==0) mnormG[b*NN+n] = sqrtf(sq);
    q = qn;
  }
  #pragma unroll
  for (int j=0;j<8;++j) lr[grp][m0+j] = racc[j];
  __syncthreads();
  if (t < MM){
    float s=0.f;
    #pragma unroll
    for (int g=0; g<16; ++g) s += lr[g][t];
    rpart[((size_t)b*SS + blockIdx.x)*MM + t] = s;
  }
}

// ---------------- kH: h = tanh(xwx + r@Wr), tiled GEMM, 2-way k-split ------
// grid (16 col-tiles, 16 b-tiles of 4) x 256 thr.
__global__ __launch_bounds__(256) void kH(
    const float* __restrict__ xwx, int tstep,
    const float* __restrict__ Wr, const float* __restrict__ rpart,
    float* __restrict__ hG, float* __restrict__ outG)
{
  const int c0 = blockIdx.x*32, b0 = blockIdx.y*4;
  const int tid = threadIdx.x;
  const int g8 = tid>>5, cc32 = tid&31;
  const int bat = g8&3, half = g8>>2;
  __shared__ float rsS[4][128];
  __shared__ float WrS[128][32];
  __shared__ float hacc[4][2][32];
  for (int lin = tid; lin < 4*128; lin += 256){
    const int rb = lin>>7, m = lin&127;
    float s = 0.f;
    #pragma unroll
    for (int ss=0; ss<SS; ++ss)
      s += rpart[((size_t)(b0+rb)*SS + ss)*MM + m];
    rsS[rb][m] = s;
  }
  for (int lin = tid; lin < 128*32; lin += 256){
    const int m = lin>>5, c = lin&31;
    WrS[m][c] = Wr[(size_t)m*HH + c0 + c];
  }
  __syncthreads();
  {
    float acc = 0.f;
    const int mb = half*64;
    #pragma unroll 8
    for (int m=0;m<64;++m) acc += rsS[bat][mb+m]*WrS[mb+m][cc32];
    hacc[bat][half][cc32] = acc;
  }
  __syncthreads();
  if (tid < 128){
    const int bat2 = tid>>5, c = tid&31;
    const float acc = hacc[bat2][0][c] + hacc[bat2][1][c]
                    + xwx[((size_t)(b0+bat2)*TT + tstep)*HH + c0 + c];
    const float hv = ftanh(acc);
    hG[(size_t)(b0+bat2)*HH + c0 + c] = hv;
    if (tstep == TT-1) outG[(size_t)(b0+bat2)*HH + c0 + c] = hv;
  }
}

// ---------------- kB2: headout = h @ Wall, tiled GEMM ----------------------
// grid (17 col-tiles, 16 b-tiles of 4) x 256 thr.
__global__ __launch_bounds__(256) void kB2(
    const float* __restrict__ hG, const float* __restrict__ Wall,
    float* __restrict__ headout)
{
  const int c0 = blockIdx.x*32, b0 = blockIdx.y*4;
  const int tid = threadIdx.x;
  const int g8 = tid>>5, cc32 = tid&31;
  const int bat = g8&3, half = g8>>2;        // half splits k-range
  __shared__ float hs[4][HH];
  __shared__ float WsS[64][32];
  __shared__ float hacc[4][2][32];
  for (int lin = tid; lin < 4*HH; lin += 256)
    hs[lin>>9][lin&511] = hG[(size_t)(b0+(lin>>9))*HH + (lin&511)];
  float acc = 0.f;
  for (int ks=0; ks<8; ++ks){
    __syncthreads();
    for (int lin = tid; lin < 64*32; lin += 256){
      const int m = lin>>5, c = lin&31;
      WsS[m][c] = Wall[(size_t)(ks*64+m)*WC + c0 + c];
    }
    __syncthreads();
    const int mbase = half*32;
    #pragma unroll 8
    for (int m=0;m<32;++m) acc += hs[bat][ks*64+mbase+m]*WsS[mbase+m][cc32];
  }
  hacc[bat][half][cc32] = acc;
  __syncthreads();
  if (tid < 128){
    const int bat2 = tid>>5, c = tid&31;
    headout[(size_t)(b0+bat2)*WC + c0 + c] = hacc[bat2][0][c] + hacc[bat2][1][c];
  }
}

// ---------------- Kernel C: content dots (wide sweep) ----------------------
__global__ __launch_bounds__(256) void kC(
    const uint4* __restrict__ mem, const float* __restrict__ headout,
    const float* __restrict__ rbk, const float* __restrict__ wbk,
    float* __restrict__ dotrG, float* __restrict__ dotwG)
{
  const int b = blockIdx.y;
  const int n0 = blockIdx.x * ROWS;
  const int t = threadIdx.x, grp=t>>4, lane=t&15;
  const int m0 = lane*8;
  const float* HO = headout + (size_t)b*WC;
  float krv[8], kwv[8];
  #pragma unroll
  for (int j=0;j<8;++j){
    krv[j] = ftanh(HO[m0+j]     + rbk[m0+j]);
    kwv[j] = ftanh(HO[128+m0+j] + wbk[m0+j]);
  }
  const size_t base4 = ((size_t)b*NN + n0)*(MM/8) + (size_t)grp*(MM/8) + lane;
  uint4 q = mem[base4];
  #pragma unroll
  for (int rr=0; rr<8; ++rr){
    uint4 qn;
    if (rr<7) qn = mem[base4 + (size_t)(rr+1)*16*(MM/8)];
    const int n = n0 + rr*16 + grp;
    float v[8];
    unpack2(q.x, v[0], v[1]); unpack2(q.y, v[2], v[3]);
    unpack2(q.z, v[4], v[5]); unpack2(q.w, v[6], v[7]);
    float dr=0.f, dw=0.f;
    #pragma unroll
    for (int j=0;j<8;++j){ dr += v[j]*krv[j]; dw += v[j]*kwv[j]; }
    #pragma unroll
    for (int msk=1; msk<16; msk<<=1){
      dr += __shfl_xor(dr, msk);
      dw += __shfl_xor(dw, msk);
    }
    if (lane==0){ dotrG[b*NN+n]=dr; dotwG[b*NN+n]=dw; }
    q = qn;
  }
}

// ---------------- Kernel D: softmax + interpolate + shift + sharpen --------
// 1024 threads, 4 elems/thread.
__device__ __forceinline__ float blockSum1024(float v, volatile float* sc){
  #pragma unroll
  for (int m=1;m<64;m<<=1) v += __shfl_xor(v,m);
  __syncthreads();
  if ((threadIdx.x&63)==0) sc[threadIdx.x>>6]=v;
  __syncthreads();
  float s=0.f;
  #pragma unroll
  for (int g=0;g<16;++g) s += sc[g];
  return s;
}

__global__ __launch_bounds__(1024) void kD(
    const float* __restrict__ dotrG, const float* __restrict__ dotwG,
    const float* __restrict__ mnormG, const float* __restrict__ headout,
    const float* __restrict__ rbk, const float* __restrict__ wbk,
    float* __restrict__ wrG, float* __restrict__ wwG)
{
  const int b = blockIdx.x, head = blockIdx.y, t = threadIdx.x;
  __shared__ float wg[NN];
  __shared__ float sc[16];
  __shared__ float sb[8];
  __shared__ float kred[2];
  const float* HO = headout + (size_t)b*WC;
  const float* bk = head? wbk : rbk;
  if (t < 128){
    const float km = ftanh(HO[head*128 + t] + bk[t]);
    float s = km*km;
    #pragma unroll
    for (int m=1;m<64;m<<=1) s += __shfl_xor(s, m);
    if ((t&63)==0) kred[t>>6]=s;
  }
  __syncthreads();
  if (t==0){
    const int sbase = 512 + head*6;
    sb[0] = softplusf_(HO[sbase+0]);        // beta
    sb[1] = fsig(HO[sbase+1]);              // g
    sb[2] = 1.f + softplusf_(HO[sbase+5]);  // gamma
    const float s0=HO[sbase+2], s1=HO[sbase+3], s2=HO[sbase+4];
    const float mx = fmaxf(s0, fmaxf(s1,s2));
    const float e0=__expf(s0-mx), e1=__expf(s1-mx), e2=__expf(s2-mx);
    const float inv3=1.f/(e0+e1+e2);
    sb[3]=e0*inv3; sb[4]=e1*inv3; sb[5]=e2*inv3;
    sb[6] = sqrtf(kred[0]+kred[1]);         // knorm
  }
  __syncthreads();
  const float* dot = head? dotwG : dotrG;
  float* wv = head? wwG : wrG;
  const float beta=sb[0], g=sb[1], gamma=sb[2];
  const float s0=sb[3], s1=sb[4], s2=sb[5], knorm=sb[6];
  // |sim| <= beta <= ~26 << 88 -> exp safe without max subtraction
  float sim[4]; float sum=0.f;
  #pragma unroll
  for (int i=0;i<4;++i){
    const int n = i*1024 + t;
    const float d  = dot[(size_t)b*NN+n];
    const float mn = mnormG[(size_t)b*NN+n];
    sim[i] = __expf(beta*d/(mn*knorm + EPSF));
    sum += sim[i];
  }
  sum = blockSum1024(sum, sc);
  const float inv = 1.f/sum;
  #pragma unroll
  for (int i=0;i<4;++i){
    const int n = i*1024 + t;
    wg[n] = g*sim[i]*inv + (1.f-g)*wv[(size_t)b*NN+n];
  }
  __syncthreads();
  float wp[4]; float ps=0.f;
  #pragma unroll
  for (int i=0;i<4;++i){
    const int n = i*1024 + t;
    const float wt = s0*wg[(n+1)&(NN-1)] + s1*wg[n] + s2*wg[(n-1)&(NN-1)];
    wp[i] = __powf(wt + EPSF, gamma);
    ps += wp[i];
  }
  ps = blockSum1024(ps, sc);
  const float ip = 1.f/ps;
  #pragma unroll
  for (int i=0;i<4;++i){
    const int n = i*1024 + t;
    wv[(size_t)b*NN+n] = wp[i]*ip;
  }
}

extern "C" void kernel_launch(void* const* d_in, const int* in_sizes, int n_in,
                              void* d_out, int out_size, void* d_ws, size_t ws_size,
                              hipStream_t stream)
{
  const float* x     = (const float*)d_in[0];
  const float* mem0  = (const float*)d_in[1];
  const float* Wx    = (const float*)d_in[2];
  const float* Wr    = (const float*)d_in[3];
  const float* bC    = (const float*)d_in[4];
  const float* rWk   = (const float*)d_in[5];
  const float* rbk   = (const float*)d_in[6];
  const float* rWbeta= (const float*)d_in[7];
  const float* rWg   = (const float*)d_in[8];
  const float* rWs   = (const float*)d_in[9];
  const float* rWgam = (const float*)d_in[10];
  const float* wWk   = (const float*)d_in[11];
  const float* wbk   = (const float*)d_in[12];
  const float* wWbeta= (const float*)d_in[13];
  const float* wWg   = (const float*)d_in[14];
  const float* wWs   = (const float*)d_in[15];
  const float* wWgam = (const float*)d_in[16];
  const float* wWe   = (const float*)d_in[17];
  const float* wWa   = (const float*)d_in[18];

  float* ws = (float*)d_ws;
  size_t o = 0;
  uint4* mem    = (uint4*)(ws + o); o += (size_t)BB*NN*MM/2;  // bf16
  float* wr     = ws + o; o += (size_t)BB*NN;
  float* ww     = ws + o; o += (size_t)BB*NN;
  float* rpart  = ws + o; o += (size_t)BB*SS*MM;
  float* mnorm  = ws + o; o += (size_t)BB*NN;
  float* dotr   = ws + o; o += (size_t)BB*NN;
  float* dotw   = ws + o; o += (size_t)BB*NN;
  float* xwx    = ws + o; o += (size_t)BB*TT*HH;
  float* hG     = ws + o; o += (size_t)BB*HH;
  float* headout= ws + o; o += (size_t)BB*WC;
  float* Wall   = ws + o; o += (size_t)HH*WC;

  kCvt<<<(BB*NN*MM/8)/256, 256, 0, stream>>>(mem0, mem);
  kInit<<<(BB*NN+255)/256, 256, 0, stream>>>(wr, ww, headout);
  kPack<<<HH, 576, 0, stream>>>(rWk, wWk, wWe, wWa,
                                rWbeta, rWg, rWs, rWgam,
                                wWbeta, wWg, wWs, wWgam, Wall);
  kPre<<<(BB*TT)/16, 512, 0, stream>>>(x, Wx, bC, xwx);

  for (int t=0; t<TT; ++t){
    kA<<<dim3(SS,BB), 256, 0, stream>>>(headout, wr, ww, mem, rpart, mnorm);
    kH<<<dim3(16,16), 256, 0, stream>>>(xwx, t, Wr, rpart, hG, (float*)d_out);
    if (t < TT-1){
      kB2<<<dim3(17,16), 256, 0, stream>>>(hG, Wall, headout);
      kC<<<dim3(SS,BB), 256, 0, stream>>>(mem, headout, rbk, wbk, dotr, dotw);
      kD<<<dim3(BB,2), 1024, 0, stream>>>(dotr, dotw, mnorm, headout,
                                          rbk, wbk, wr, ww);
    }
  }
}

// Round 15
// 4516.406 us; speedup vs baseline: 1.0004x; 1.0004x over previous
//
#include <hip/hip_runtime.h>
#include <hip/hip_bf16.h>
#include <math.h>

#define BB 64
#define TT 64
#define INDIM 256
#define HH 512
#define NN 4096
#define MM 128
#define SS 32            // sweep slabs per batch
#define ROWS 128         // rows per sweep block = NN/SS
#define WC 544           // packed head-weight columns (512 + 12 + pad)
#define EPSF 1e-8f

__device__ __forceinline__ float fsig(float x){ return 1.f/(1.f+__expf(-x)); }
__device__ __forceinline__ float ftanh(float x){ return 1.f - 2.f/(__expf(2.f*x)+1.f); }
__device__ __forceinline__ float softplusf_(float x){ return (x>20.f)? x : log1pf(expf(x)); }

__device__ __forceinline__ void unpack2(unsigned u, float& lo, float& hi){
  lo = __uint_as_float(u << 16);
  hi = __uint_as_float(u & 0xffff0000u);
}
__device__ __forceinline__ unsigned packrn(float a, float b){
  __hip_bfloat162 p = __float22bfloat162_rn(make_float2(a,b));
  return *reinterpret_cast<unsigned*>(&p);
}

// ---------------- kCvt: fp32 mem0 -> bf16 mem (once) -----------------------
__global__ __launch_bounds__(256) void kCvt(const float* __restrict__ src,
                                            uint4* __restrict__ dst){
  const size_t i = (size_t)blockIdx.x*blockDim.x + threadIdx.x;
  const float4 f0 = *(const float4*)(src + i*8);
  const float4 f1 = *(const float4*)(src + i*8 + 4);
  uint4 q;
  q.x = packrn(f0.x, f0.y); q.y = packrn(f0.z, f0.w);
  q.z = packrn(f1.x, f1.y); q.w = packrn(f1.z, f1.w);
  dst[i] = q;
}

// ---------------- kInit (once) ---------------------------------------------
__global__ void kInit(float* wr, float* ww, float* headout){
  const int i = blockIdx.x*blockDim.x + threadIdx.x;
  if (i < BB*NN){ const float v = (i==0)? 1.f : 0.f; wr[i]=v; ww[i]=v; }
  if (i < BB*WC) headout[i]=0.f;   // h0=0 -> raw head outputs 0
}

// ---------------- kPack: concat head weights into Wall[512][544] (once) ----
__global__ __launch_bounds__(576) void kPack(
    const float* __restrict__ rWk, const float* __restrict__ wWk,
    const float* __restrict__ wWe, const float* __restrict__ wWa,
    const float* __restrict__ rWbeta, const float* __restrict__ rWg,
    const float* __restrict__ rWs, const float* __restrict__ rWgam,
    const float* __restrict__ wWbeta, const float* __restrict__ wWg,
    const float* __restrict__ wWs, const float* __restrict__ wWgam,
    float* __restrict__ Wall)
{
  const int j = blockIdx.x, c = threadIdx.x;
  if (c >= WC) return;
  float v = 0.f;
  if      (c < 128) v = rWk[(size_t)j*128 + c];
  else if (c < 256) v = wWk[(size_t)j*128 + c-128];
  else if (c < 384) v = wWe[(size_t)j*128 + c-256];
  else if (c < 512) v = wWa[(size_t)j*128 + c-384];
  else {
    const int cc = c - 512;
    switch (cc){
      case 0:  v = rWbeta[j]; break;
      case 1:  v = rWg[j];    break;
      case 2: case 3: case 4: v = rWs[(size_t)j*3 + cc-2]; break;
      case 5:  v = rWgam[j];  break;
      case 6:  v = wWbeta[j]; break;
      case 7:  v = wWg[j];    break;
      case 8: case 9: case 10: v = wWs[(size_t)j*3 + cc-8]; break;
      case 11: v = wWgam[j];  break;
      default: v = 0.f; break;
    }
  }
  Wall[(size_t)j*WC + c] = v;
}

// ---------------- kPre: xwx = bC + x@Wx, 16 bt-rows per block (once) -------
__global__ __launch_bounds__(512) void kPre(const float* __restrict__ x,
                                            const float* __restrict__ Wx,
                                            const float* __restrict__ bC,
                                            float* __restrict__ xwx){
  const int bt0 = blockIdx.x*16, t = threadIdx.x;
  __shared__ float xs[INDIM][16];
  for (int lin = t; lin < 16*INDIM; lin += 512){
    const int ii = lin & 255, r = lin >> 8;
    xs[ii][r] = x[(size_t)(bt0+r)*INDIM + ii];
  }
  __syncthreads();
  float accv[16];
  #pragma unroll
  for (int r=0;r<16;++r) accv[r]=0.f;
  for (int ii=0; ii<INDIM; ++ii){
    const float w = Wx[(size_t)ii*HH + t];
    const float4* xp = (const float4*)&xs[ii][0];
    const float4 x0=xp[0], x1=xp[1], x2=xp[2], x3=xp[3];
    accv[0]+=x0.x*w; accv[1]+=x0.y*w; accv[2]+=x0.z*w; accv[3]+=x0.w*w;
    accv[4]+=x1.x*w; accv[5]+=x1.y*w; accv[6]+=x1.z*w; accv[7]+=x1.w*w;
    accv[8]+=x2.x*w; accv[9]+=x2.y*w; accv[10]+=x2.z*w; accv[11]+=x2.w*w;
    accv[12]+=x3.x*w; accv[13]+=x3.y*w; accv[14]+=x3.z*w; accv[15]+=x3.w*w;
  }
  const float bc = bC[t];
  #pragma unroll
  for (int r=0;r<16;++r)
    xwx[(size_t)(bt0+r)*HH + t] = accv[r] + bc;
}

// ---------------- Kernel A: mem update + r partials ------------------------
__global__ __launch_bounds__(256) void kA(
    const float* __restrict__ headout,
    const float* __restrict__ wrG, const float* __restrict__ wwG,
    uint4* __restrict__ mem, float* __restrict__ rpart)
{
  const int b = blockIdx.y;
  const int n0 = blockIdx.x * ROWS;
  const int t = threadIdx.x;
  const int grp = t >> 4, lane = t & 15;
  const int m0 = lane * 8;
  const float* HO = headout + (size_t)b*WC;
  float ev[8], av[8];
  #pragma unroll
  for (int j=0;j<8;++j){
    ev[j] = fsig (HO[256 + m0 + j]);
    av[j] = ftanh(HO[384 + m0 + j]);
  }
  float wwv[8], wrv[8];
  #pragma unroll
  for (int rr=0; rr<8; ++rr){
    const int n = n0 + rr*16 + grp;
    wwv[rr] = wwG[b*NN+n];
    wrv[rr] = wrG[b*NN+n];
  }
  float racc[8];
  #pragma unroll
  for (int j=0;j<8;++j) racc[j]=0.f;
  __shared__ float lr[16][128];
  const size_t base4 = ((size_t)b*NN + n0)*(MM/8) + (size_t)grp*(MM/8) + lane;
  uint4 q = mem[base4];
  #pragma unroll
  for (int rr=0; rr<8; ++rr){
    uint4 qn;
    if (rr<7) qn = mem[base4 + (size_t)(rr+1)*16*(MM/8)];
    float v[8];
    unpack2(q.x, v[0], v[1]); unpack2(q.y, v[2], v[3]);
    unpack2(q.z, v[4], v[5]); unpack2(q.w, v[6], v[7]);
    const float w = wwv[rr], wr_ = wrv[rr];
    #pragma unroll
    for (int j=0;j<8;++j){
      v[j] = v[j]*(1.f - w*ev[j]) + w*av[j];
      racc[j] += wr_*v[j];
    }
    uint4 q2;
    q2.x = packrn(v[0],v[1]); q2.y = packrn(v[2],v[3]);
    q2.z = packrn(v[4],v[5]); q2.w = packrn(v[6],v[7]);
    mem[base4 + (size_t)rr*16*(MM/8)] = q2;
    q = qn;
  }
  #pragma unroll
  for (int j=0;j<8;++j) lr[grp][m0+j] = racc[j];
  __syncthreads();
  if (t < MM){
    float s=0.f;
    #pragma unroll
    for (int g=0; g<16; ++g) s += lr[g][t];
    rpart[((size_t)b*SS + blockIdx.x)*MM + t] = s;
  }
}

// ---------------- kH: h = tanh(xwx + r@Wr), tiled GEMM, 2-way k-split ------
// grid (16 col-tiles, 16 b-tiles of 4) x 256 thr.
__global__ __launch_bounds__(256) void kH(
    const float* __restrict__ xwx, int tstep,
    const float* __restrict__ Wr, const float* __restrict__ rpart,
    float* __restrict__ hG, float* __restrict__ outG)
{
  const int c0 = blockIdx.x*32, b0 = blockIdx.y*4;
  const int tid = threadIdx.x;
  const int g8 = tid>>5, cc32 = tid&31;
  const int bat = g8&3, half = g8>>2;
  __shared__ float rsS[4][128];
  __shared__ float WrS[128][32];
  __shared__ float hacc[4][2][32];
  for (int lin = tid; lin < 4*128; lin += 256){
    const int rb = lin>>7, m = lin&127;
    float s = 0.f;
    #pragma unroll
    for (int ss=0; ss<SS; ++ss)
      s += rpart[((size_t)(b0+rb)*SS + ss)*MM + m];
    rsS[rb][m] = s;
  }
  for (int lin = tid; lin < 128*32; lin += 256){
    const int m = lin>>5, c = lin&31;
    WrS[m][c] = Wr[(size_t)m*HH + c0 + c];
  }
  __syncthreads();
  {
    float acc = 0.f;
    const int mb = half*64;
    #pragma unroll 8
    for (int m=0;m<64;++m) acc += rsS[bat][mb+m]*WrS[mb+m][cc32];
    hacc[bat][half][cc32] = acc;
  }
  __syncthreads();
  if (tid < 128){
    const int bat2 = tid>>5, c = tid&31;
    const float acc = hacc[bat2][0][c] + hacc[bat2][1][c]
                    + xwx[((size_t)(b0+bat2)*TT + tstep)*HH + c0 + c];
    const float hv = ftanh(acc);
    hG[(size_t)(b0+bat2)*HH + c0 + c] = hv;
    if (tstep == TT-1) outG[(size_t)(b0+bat2)*HH + c0 + c] = hv;
  }
}

// ---------------- kB2: headout = h @ Wall, tiled GEMM ----------------------
// grid (17 col-tiles, 16 b-tiles of 4) x 256 thr.
__global__ __launch_bounds__(256) void kB2(
    const float* __restrict__ hG, const float* __restrict__ Wall,
    float* __restrict__ headout)
{
  const int c0 = blockIdx.x*32, b0 = blockIdx.y*4;
  const int tid = threadIdx.x;
  const int g8 = tid>>5, cc32 = tid&31;
  const int bat = g8&3, half = g8>>2;        // half splits k-range
  __shared__ float hs[4][HH];
  __shared__ float WsS[64][32];
  __shared__ float hacc[4][2][32];
  for (int lin = tid; lin < 4*HH; lin += 256)
    hs[lin>>9][lin&511] = hG[(size_t)(b0+(lin>>9))*HH + (lin&511)];
  float acc = 0.f;
  for (int ks=0; ks<8; ++ks){
    __syncthreads();
    for (int lin = tid; lin < 64*32; lin += 256){
      const int m = lin>>5, c = lin&31;
      WsS[m][c] = Wall[(size_t)(ks*64+m)*WC + c0 + c];
    }
    __syncthreads();
    const int mbase = half*32;
    #pragma unroll 8
    for (int m=0;m<32;++m) acc += hs[bat][ks*64+mbase+m]*WsS[mbase+m][cc32];
  }
  hacc[bat][half][cc32] = acc;
  __syncthreads();
  if (tid < 128){
    const int bat2 = tid>>5, c = tid&31;
    headout[(size_t)(b0+bat2)*WC + c0 + c] = hacc[bat2][0][c] + hacc[bat2][1][c];
  }
}

// ---------------- Kernel C: content dots + mnorm (wide sweep) --------------
__global__ __launch_bounds__(256) void kC(
    const uint4* __restrict__ mem, const float* __restrict__ headout,
    const float* __restrict__ rbk, const float* __restrict__ wbk,
    float* __restrict__ dotrG, float* __restrict__ dotwG,
    float* __restrict__ mnormG)
{
  const int b = blockIdx.y;
  const int n0 = blockIdx.x * ROWS;
  const int t = threadIdx.x, grp=t>>4, lane=t&15;
  const int m0 = lane*8;
  const float* HO = headout + (size_t)b*WC;
  float krv[8], kwv[8];
  #pragma unroll
  for (int j=0;j<8;++j){
    krv[j] = ftanh(HO[m0+j]     + rbk[m0+j]);
    kwv[j] = ftanh(HO[128+m0+j] + wbk[m0+j]);
  }
  const size_t base4 = ((size_t)b*NN + n0)*(MM/8) + (size_t)grp*(MM/8) + lane;
  uint4 q = mem[base4];
  #pragma unroll
  for (int rr=0; rr<8; ++rr){
    uint4 qn;
    if (rr<7) qn = mem[base4 + (size_t)(rr+1)*16*(MM/8)];
    const int n = n0 + rr*16 + grp;
    float v[8];
    unpack2(q.x, v[0], v[1]); unpack2(q.y, v[2], v[3]);
    unpack2(q.z, v[4], v[5]); unpack2(q.w, v[6], v[7]);
    float dr=0.f, dw=0.f, sq=0.f;
    #pragma unroll
    for (int j=0;j<8;++j){
      dr += v[j]*krv[j]; dw += v[j]*kwv[j]; sq += v[j]*v[j];
    }
    #pragma unroll
    for (int msk=1; msk<16; msk<<=1){
      dr += __shfl_xor(dr, msk);
      dw += __shfl_xor(dw, msk);
      sq += __shfl_xor(sq, msk);
    }
    if (lane==0){
      dotrG[b*NN+n]=dr; dotwG[b*NN+n]=dw; mnormG[b*NN+n]=sqrtf(sq);
    }
    q = qn;
  }
}

// ---------------- Kernel D: softmax + interpolate + shift + sharpen --------
// 1024 threads, 4 elems/thread.
__device__ __forceinline__ float blockSum1024(float v, volatile float* sc){
  #pragma unroll
  for (int m=1;m<64;m<<=1) v += __shfl_xor(v,m);
  __syncthreads();
  if ((threadIdx.x&63)==0) sc[threadIdx.x>>6]=v;
  __syncthreads();
  float s=0.f;
  #pragma unroll
  for (int g=0;g<16;++g) s += sc[g];
  return s;
}

__global__ __launch_bounds__(1024) void kD(
    const float* __restrict__ dotrG, const float* __restrict__ dotwG,
    const float* __restrict__ mnormG, const float* __restrict__ headout,
    const float* __restrict__ rbk, const float* __restrict__ wbk,
    float* __restrict__ wrG, float* __restrict__ wwG)
{
  const int b = blockIdx.x, head = blockIdx.y, t = threadIdx.x;
  __shared__ float wg[NN];
  __shared__ float sc[16];
  __shared__ float sb[8];
  __shared__ float kred[2];
  const float* HO = headout + (size_t)b*WC;
  const float* bk = head? wbk : rbk;
  if (t < 128){
    const float km = ftanh(HO[head*128 + t] + bk[t]);
    float s = km*km;
    #pragma unroll
    for (int m=1;m<64;m<<=1) s += __shfl_xor(s, m);
    if ((t&63)==0) kred[t>>6]=s;
  }
  __syncthreads();
  if (t==0){
    const int sbase = 512 + head*6;
    sb[0] = softplusf_(HO[sbase+0]);        // beta
    sb[1] = fsig(HO[sbase+1]);              // g
    sb[2] = 1.f + softplusf_(HO[sbase+5]);  // gamma
    const float s0=HO[sbase+2], s1=HO[sbase+3], s2=HO[sbase+4];
    const float mx = fmaxf(s0, fmaxf(s1,s2));
    const float e0=__expf(s0-mx), e1=__expf(s1-mx), e2=__expf(s2-mx);
    const float inv3=1.f/(e0+e1+e2);
    sb[3]=e0*inv3; sb[4]=e1*inv3; sb[5]=e2*inv3;
    sb[6] = sqrtf(kred[0]+kred[1]);         // knorm
  }
  __syncthreads();
  const float* dot = head? dotwG : dotrG;
  float* wv = head? wwG : wrG;
  const float beta=sb[0], g=sb[1], gamma=sb[2];
  const float s0=sb[3], s1=sb[4], s2=sb[5], knorm=sb[6];
  // |sim| <= beta <= ~26 << 88 -> exp safe without max subtraction
  float sim[4]; float sum=0.f;
  #pragma unroll
  for (int i=0;i<4;++i){
    const int n = i*1024 + t;
    const float d  = dot[(size_t)b*NN+n];
    const float mn = mnormG[(size_t)b*NN+n];
    sim[i] = __expf(beta*d/(mn*knorm + EPSF));
    sum += sim[i];
  }
  sum = blockSum1024(sum, sc);
  const float inv = 1.f/sum;
  #pragma unroll
  for (int i=0;i<4;++i){
    const int n = i*1024 + t;
    wg[n] = g*sim[i]*inv + (1.f-g)*wv[(size_t)b*NN+n];
  }
  __syncthreads();
  float wp[4]; float ps=0.f;
  #pragma unroll
  for (int i=0;i<4;++i){
    const int n = i*1024 + t;
    const float wt = s0*wg[(n+1)&(NN-1)] + s1*wg[n] + s2*wg[(n-1)&(NN-1)];
    wp[i] = __powf(wt + EPSF, gamma);
    ps += wp[i];
  }
  ps = blockSum1024(ps, sc);
  const float ip = 1.f/ps;
  #pragma unroll
  for (int i=0;i<4;++i){
    const int n = i*1024 + t;
    wv[(size_t)b*NN+n] = wp[i]*ip;
  }
}

extern "C" void kernel_launch(void* const* d_in, const int* in_sizes, int n_in,
                              void* d_out, int out_size, void* d_ws, size_t ws_size,
                              hipStream_t stream)
{
  const float* x     = (const float*)d_in[0];
  const float* mem0  = (const float*)d_in[1];
  const float* Wx    = (const float*)d_in[2];
  const float* Wr    = (const float*)d_in[3];
  const float* bC    = (const float*)d_in[4];
  const float* rWk   = (const float*)d_in[5];
  const float* rbk   = (const float*)d_in[6];
  const float* rWbeta= (const float*)d_in[7];
  const float* rWg   = (const float*)d_in[8];
  const float* rWs   = (const float*)d_in[9];
  const float* rWgam = (const float*)d_in[10];
  const float* wWk   = (const float*)d_in[11];
  const float* wbk   = (const float*)d_in[12];
  const float* wWbeta= (const float*)d_in[13];
  const float* wWg   = (const float*)d_in[14];
  const float* wWs   = (const float*)d_in[15];
  const float* wWgam = (const float*)d_in[16];
  const float* wWe   = (const float*)d_in[17];
  const float* wWa   = (const float*)d_in[18];

  float* ws = (float*)d_ws;
  size_t o = 0;
  uint4* mem    = (uint4*)(ws + o); o += (size_t)BB*NN*MM/2;  // bf16
  float* wr     = ws + o; o += (size_t)BB*NN;
  float* ww     = ws + o; o += (size_t)BB*NN;
  float* rpart  = ws + o; o += (size_t)BB*SS*MM;
  float* mnorm  = ws + o; o += (size_t)BB*NN;
  float* dotr   = ws + o; o += (size_t)BB*NN;
  float* dotw   = ws + o; o += (size_t)BB*NN;
  float* xwx    = ws + o; o += (size_t)BB*TT*HH;
  float* hG     = ws + o; o += (size_t)BB*HH;
  float* headout= ws + o; o += (size_t)BB*WC;
  float* Wall   = ws + o; o += (size_t)HH*WC;

  kCvt<<<(BB*NN*MM/8)/256, 256, 0, stream>>>(mem0, mem);
  kInit<<<(BB*NN+255)/256, 256, 0, stream>>>(wr, ww, headout);
  kPack<<<HH, 576, 0, stream>>>(rWk, wWk, wWe, wWa,
                                rWbeta, rWg, rWs, rWgam,
                                wWbeta, wWg, wWs, wWgam, Wall);
  kPre<<<(BB*TT)/16, 512, 0, stream>>>(x, Wx, bC, xwx);

  for (int t=0; t<TT; ++t){
    kA<<<dim3(SS,BB), 256, 0, stream>>>(headout, wr, ww, mem, rpart);
    kH<<<dim3(16,16), 256, 0, stream>>>(xwx, t, Wr, rpart, hG, (float*)d_out);
    if (t < TT-1){
      kB2<<<dim3(17,16), 256, 0, stream>>>(hG, Wall, headout);
      kC<<<dim3(SS,BB), 256, 0, stream>>>(mem, headout, rbk, wbk,
                                          dotr, dotw, mnorm);
      kD<<<dim3(BB,2), 1024, 0, stream>>>(dotr, dotw, mnorm, headout,
                                          rbk, wbk, wr, ww);
    }
  }
}

// Round 16
// 4429.350 us; speedup vs baseline: 1.0201x; 1.0197x over previous
//
#include <hip/hip_runtime.h>
#include <hip/hip_bf16.h>
#include <math.h>

#define BB 64
#define TT 64
#define INDIM 256
#define HH 512
#define NN 4096
#define MM 128
#define SS 32            // sweep slabs per batch
#define ROWS 128         // rows per sweep block = NN/SS
#define WC 544           // packed head-weight columns (512 + 12 + pad)
#define EPSF 1e-8f

__device__ __forceinline__ float fsig(float x){ return 1.f/(1.f+__expf(-x)); }
__device__ __forceinline__ float ftanh(float x){ return 1.f - 2.f/(__expf(2.f*x)+1.f); }
__device__ __forceinline__ float softplusf_(float x){ return (x>20.f)? x : log1pf(expf(x)); }

__device__ __forceinline__ void unpack2(unsigned u, float& lo, float& hi){
  lo = __uint_as_float(u << 16);
  hi = __uint_as_float(u & 0xffff0000u);
}
__device__ __forceinline__ unsigned packrn(float a, float b){
  __hip_bfloat162 p = __float22bfloat162_rn(make_float2(a,b));
  return *reinterpret_cast<unsigned*>(&p);
}

// ---------------- kCvt: fp32 mem0 -> bf16 mem (once) -----------------------
__global__ __launch_bounds__(256) void kCvt(const float* __restrict__ src,
                                            uint4* __restrict__ dst){
  const size_t i = (size_t)blockIdx.x*blockDim.x + threadIdx.x;
  const float4 f0 = *(const float4*)(src + i*8);
  const float4 f1 = *(const float4*)(src + i*8 + 4);
  uint4 q;
  q.x = packrn(f0.x, f0.y); q.y = packrn(f0.z, f0.w);
  q.z = packrn(f1.x, f1.y); q.w = packrn(f1.z, f1.w);
  dst[i] = q;
}

// ---------------- kInit (once) ---------------------------------------------
__global__ void kInit(float* wr, float* ww, float* headout){
  const int i = blockIdx.x*blockDim.x + threadIdx.x;
  if (i < BB*NN){ const float v = (i==0)? 1.f : 0.f; wr[i]=v; ww[i]=v; }
  if (i < BB*WC) headout[i]=0.f;   // h0=0 -> raw head outputs 0
}

// ---------------- kPack: concat head weights into Wall[512][544] (once) ----
__global__ __launch_bounds__(576) void kPack(
    const float* __restrict__ rWk, const float* __restrict__ wWk,
    const float* __restrict__ wWe, const float* __restrict__ wWa,
    const float* __restrict__ rWbeta, const float* __restrict__ rWg,
    const float* __restrict__ rWs, const float* __restrict__ rWgam,
    const float* __restrict__ wWbeta, const float* __restrict__ wWg,
    const float* __restrict__ wWs, const float* __restrict__ wWgam,
    float* __restrict__ Wall)
{
  const int j = blockIdx.x, c = threadIdx.x;
  if (c >= WC) return;
  float v = 0.f;
  if      (c < 128) v = rWk[(size_t)j*128 + c];
  else if (c < 256) v = wWk[(size_t)j*128 + c-128];
  else if (c < 384) v = wWe[(size_t)j*128 + c-256];
  else if (c < 512) v = wWa[(size_t)j*128 + c-384];
  else {
    const int cc = c - 512;
    switch (cc){
      case 0:  v = rWbeta[j]; break;
      case 1:  v = rWg[j];    break;
      case 2: case 3: case 4: v = rWs[(size_t)j*3 + cc-2]; break;
      case 5:  v = rWgam[j];  break;
      case 6:  v = wWbeta[j]; break;
      case 7:  v = wWg[j];    break;
      case 8: case 9: case 10: v = wWs[(size_t)j*3 + cc-8]; break;
      case 11: v = wWgam[j];  break;
      default: v = 0.f; break;
    }
  }
  Wall[(size_t)j*WC + c] = v;
}

// ---------------- kPre: xwx = bC + x@Wx, 16 bt-rows per block (once) -------
__global__ __launch_bounds__(512) void kPre(const float* __restrict__ x,
                                            const float* __restrict__ Wx,
                                            const float* __restrict__ bC,
                                            float* __restrict__ xwx){
  const int bt0 = blockIdx.x*16, t = threadIdx.x;
  __shared__ float xs[INDIM][16];
  for (int lin = t; lin < 16*INDIM; lin += 512){
    const int ii = lin & 255, r = lin >> 8;
    xs[ii][r] = x[(size_t)(bt0+r)*INDIM + ii];
  }
  __syncthreads();
  float accv[16];
  #pragma unroll
  for (int r=0;r<16;++r) accv[r]=0.f;
  for (int ii=0; ii<INDIM; ++ii){
    const float w = Wx[(size_t)ii*HH + t];
    const float4* xp = (const float4*)&xs[ii][0];
    const float4 x0=xp[0], x1=xp[1], x2=xp[2], x3=xp[3];
    accv[0]+=x0.x*w; accv[1]+=x0.y*w; accv[2]+=x0.z*w; accv[3]+=x0.w*w;
    accv[4]+=x1.x*w; accv[5]+=x1.y*w; accv[6]+=x1.z*w; accv[7]+=x1.w*w;
    accv[8]+=x2.x*w; accv[9]+=x2.y*w; accv[10]+=x2.z*w; accv[11]+=x2.w*w;
    accv[12]+=x3.x*w; accv[13]+=x3.y*w; accv[14]+=x3.z*w; accv[15]+=x3.w*w;
  }
  const float bc = bC[t];
  #pragma unroll
  for (int r=0;r<16;++r)
    xwx[(size_t)(bt0+r)*HH + t] = accv[r] + bc;
}

// ---------------- Kernel A: mem update + r partials + mnorm ----------------
__global__ __launch_bounds__(256) void kA(
    const float* __restrict__ headout,
    const float* __restrict__ wrG, const float* __restrict__ wwG,
    uint4* __restrict__ mem, float* __restrict__ rpart, float* __restrict__ mnormG)
{
  const int b = blockIdx.y;
  const int n0 = blockIdx.x * ROWS;
  const int t = threadIdx.x;
  const int grp = t >> 4, lane = t & 15;
  const int m0 = lane * 8;
  const float* HO = headout + (size_t)b*WC;
  float ev[8], av[8];
  #pragma unroll
  for (int j=0;j<8;++j){
    ev[j] = fsig (HO[256 + m0 + j]);
    av[j] = ftanh(HO[384 + m0 + j]);
  }
  float wwv[8], wrv[8];
  #pragma unroll
  for (int rr=0; rr<8; ++rr){
    const int n = n0 + rr*16 + grp;
    wwv[rr] = wwG[b*NN+n];
    wrv[rr] = wrG[b*NN+n];
  }
  float racc[8];
  #pragma unroll
  for (int j=0;j<8;++j) racc[j]=0.f;
  __shared__ float lr[16][128];
  const size_t base4 = ((size_t)b*NN + n0)*(MM/8) + (size_t)grp*(MM/8) + lane;
  uint4 q = mem[base4];
  #pragma unroll
  for (int rr=0; rr<8; ++rr){
    uint4 qn;
    if (rr<7) qn = mem[base4 + (size_t)(rr+1)*16*(MM/8)];
    const int n = n0 + rr*16 + grp;
    float v[8];
    unpack2(q.x, v[0], v[1]); unpack2(q.y, v[2], v[3]);
    unpack2(q.z, v[4], v[5]); unpack2(q.w, v[6], v[7]);
    float sq = 0.f;
    const float w = wwv[rr], wr_ = wrv[rr];
    #pragma unroll
    for (int j=0;j<8;++j){
      v[j] = v[j]*(1.f - w*ev[j]) + w*av[j];
      racc[j] += wr_*v[j];
      sq += v[j]*v[j];
    }
    uint4 q2;
    q2.x = packrn(v[0],v[1]); q2.y = packrn(v[2],v[3]);
    q2.z = packrn(v[4],v[5]); q2.w = packrn(v[6],v[7]);
    mem[base4 + (size_t)rr*16*(MM/8)] = q2;
    #pragma unroll
    for (int msk=1; msk<16; msk<<=1) sq += __shfl_xor(sq, msk);
    if (lane==0) mnormG[b*NN+n] = sqrtf(sq);
    q = qn;
  }
  #pragma unroll
  for (int j=0;j<8;++j) lr[grp][m0+j] = racc[j];
  __syncthreads();
  if (t < MM){
    float s=0.f;
    #pragma unroll
    for (int g=0; g<16; ++g) s += lr[g][t];
    rpart[((size_t)b*SS + blockIdx.x)*MM + t] = s;
  }
}

// ---------------- kH: h = tanh(xwx + r@Wr), tiled GEMM, 2-way k-split ------
// grid (16 col-tiles, 16 b-tiles of 4) x 256 thr.
__global__ __launch_bounds__(256) void kH(
    const float* __restrict__ xwx, int tstep,
    const float* __restrict__ Wr, const float* __restrict__ rpart,
    float* __restrict__ hG, float* __restrict__ outG)
{
  const int c0 = blockIdx.x*32, b0 = blockIdx.y*4;
  const int tid = threadIdx.x;
  const int g8 = tid>>5, cc32 = tid&31;
  const int bat = g8&3, half = g8>>2;
  __shared__ float rsS[4][128];
  __shared__ float WrS[128][32];
  __shared__ float hacc[4][2][32];
  for (int lin = tid; lin < 4*128; lin += 256){
    const int rb = lin>>7, m = lin&127;
    float s = 0.f;
    #pragma unroll
    for (int ss=0; ss<SS; ++ss)
      s += rpart[((size_t)(b0+rb)*SS + ss)*MM + m];
    rsS[rb][m] = s;
  }
  for (int lin = tid; lin < 128*32; lin += 256){
    const int m = lin>>5, c = lin&31;
    WrS[m][c] = Wr[(size_t)m*HH + c0 + c];
  }
  __syncthreads();
  {
    float acc = 0.f;
    const int mb = half*64;
    #pragma unroll 8
    for (int m=0;m<64;++m) acc += rsS[bat][mb+m]*WrS[mb+m][cc32];
    hacc[bat][half][cc32] = acc;
  }
  __syncthreads();
  if (tid < 128){
    const int bat2 = tid>>5, c = tid&31;
    const float acc = hacc[bat2][0][c] + hacc[bat2][1][c]
                    + xwx[((size_t)(b0+bat2)*TT + tstep)*HH + c0 + c];
    const float hv = ftanh(acc);
    hG[(size_t)(b0+bat2)*HH + c0 + c] = hv;
    if (tstep == TT-1) outG[(size_t)(b0+bat2)*HH + c0 + c] = hv;
  }
}

// ---------------- kB2: headout = h @ Wall, tiled GEMM ----------------------
// grid (17 col-tiles, 16 b-tiles of 4) x 256 thr.
__global__ __launch_bounds__(256) void kB2(
    const float* __restrict__ hG, const float* __restrict__ Wall,
    float* __restrict__ headout)
{
  const int c0 = blockIdx.x*32, b0 = blockIdx.y*4;
  const int tid = threadIdx.x;
  const int g8 = tid>>5, cc32 = tid&31;
  const int bat = g8&3, half = g8>>2;        // half splits k-range
  __shared__ float hs[4][HH];
  __shared__ float WsS[64][32];
  __shared__ float hacc[4][2][32];
  for (int lin = tid; lin < 4*HH; lin += 256)
    hs[lin>>9][lin&511] = hG[(size_t)(b0+(lin>>9))*HH + (lin&511)];
  float acc = 0.f;
  for (int ks=0; ks<8; ++ks){
    __syncthreads();
    for (int lin = tid; lin < 64*32; lin += 256){
      const int m = lin>>5, c = lin&31;
      WsS[m][c] = Wall[(size_t)(ks*64+m)*WC + c0 + c];
    }
    __syncthreads();
    const int mbase = half*32;
    #pragma unroll 8
    for (int m=0;m<32;++m) acc += hs[bat][ks*64+mbase+m]*WsS[mbase+m][cc32];
  }
  hacc[bat][half][cc32] = acc;
  __syncthreads();
  if (tid < 128){
    const int bat2 = tid>>5, c = tid&31;
    headout[(size_t)(b0+bat2)*WC + c0 + c] = hacc[bat2][0][c] + hacc[bat2][1][c];
  }
}

// ---------------- Kernel C: content dots (wide sweep) ----------------------
__global__ __launch_bounds__(256) void kC(
    const uint4* __restrict__ mem, const float* __restrict__ headout,
    const float* __restrict__ rbk, const float* __restrict__ wbk,
    float* __restrict__ dotrG, float* __restrict__ dotwG)
{
  const int b = blockIdx.y;
  const int n0 = blockIdx.x * ROWS;
  const int t = threadIdx.x, grp=t>>4, lane=t&15;
  const int m0 = lane*8;
  const float* HO = headout + (size_t)b*WC;
  float krv[8], kwv[8];
  #pragma unroll
  for (int j=0;j<8;++j){
    krv[j] = ftanh(HO[m0+j]     + rbk[m0+j]);
    kwv[j] = ftanh(HO[128+m0+j] + wbk[m0+j]);
  }
  const size_t base4 = ((size_t)b*NN + n0)*(MM/8) + (size_t)grp*(MM/8) + lane;
  uint4 q = mem[base4];
  #pragma unroll
  for (int rr=0; rr<8; ++rr){
    uint4 qn;
    if (rr<7) qn = mem[base4 + (size_t)(rr+1)*16*(MM/8)];
    const int n = n0 + rr*16 + grp;
    float v[8];
    unpack2(q.x, v[0], v[1]); unpack2(q.y, v[2], v[3]);
    unpack2(q.z, v[4], v[5]); unpack2(q.w, v[6], v[7]);
    float dr=0.f, dw=0.f;
    #pragma unroll
    for (int j=0;j<8;++j){ dr += v[j]*krv[j]; dw += v[j]*kwv[j]; }
    #pragma unroll
    for (int msk=1; msk<16; msk<<=1){
      dr += __shfl_xor(dr, msk);
      dw += __shfl_xor(dw, msk);
    }
    if (lane==0){ dotrG[b*NN+n]=dr; dotwG[b*NN+n]=dw; }
    q = qn;
  }
}

// ---------------- Kernel D: softmax + interpolate + shift + sharpen --------
// 1024 threads, 4 elems/thread.
__device__ __forceinline__ float blockSum1024(float v, volatile float* sc){
  #pragma unroll
  for (int m=1;m<64;m<<=1) v += __shfl_xor(v,m);
  __syncthreads();
  if ((threadIdx.x&63)==0) sc[threadIdx.x>>6]=v;
  __syncthreads();
  float s=0.f;
  #pragma unroll
  for (int g=0;g<16;++g) s += sc[g];
  return s;
}

__global__ __launch_bounds__(1024) void kD(
    const float* __restrict__ dotrG, const float* __restrict__ dotwG,
    const float* __restrict__ mnormG, const float* __restrict__ headout,
    const float* __restrict__ rbk, const float* __restrict__ wbk,
    float* __restrict__ wrG, float* __restrict__ wwG)
{
  const int b = blockIdx.x, head = blockIdx.y, t = threadIdx.x;
  __shared__ float wg[NN];
  __shared__ float sc[16];
  __shared__ float sb[8];
  __shared__ float kred[2];
  const float* HO = headout + (size_t)b*WC;
  const float* bk = head? wbk : rbk;
  if (t < 128){
    const float km = ftanh(HO[head*128 + t] + bk[t]);
    float s = km*km;
    #pragma unroll
    for (int m=1;m<64;m<<=1) s += __shfl_xor(s, m);
    if ((t&63)==0) kred[t>>6]=s;
  }
  __syncthreads();
  if (t==0){
    const int sbase = 512 + head*6;
    sb[0] = softplusf_(HO[sbase+0]);        // beta
    sb[1] = fsig(HO[sbase+1]);              // g
    sb[2] = 1.f + softplusf_(HO[sbase+5]);  // gamma
    const float s0=HO[sbase+2], s1=HO[sbase+3], s2=HO[sbase+4];
    const float mx = fmaxf(s0, fmaxf(s1,s2));
    const float e0=__expf(s0-mx), e1=__expf(s1-mx), e2=__expf(s2-mx);
    const float inv3=1.f/(e0+e1+e2);
    sb[3]=e0*inv3; sb[4]=e1*inv3; sb[5]=e2*inv3;
    sb[6] = sqrtf(kred[0]+kred[1]);         // knorm
  }
  __syncthreads();
  const float* dot = head? dotwG : dotrG;
  float* wv = head? wwG : wrG;
  const float beta=sb[0], g=sb[1], gamma=sb[2];
  const float s0=sb[3], s1=sb[4], s2=sb[5], knorm=sb[6];
  // |sim| <= beta <= ~26 << 88 -> exp safe without max subtraction
  float sim[4]; float sum=0.f;
  #pragma unroll
  for (int i=0;i<4;++i){
    const int n = i*1024 + t;
    const float d  = dot[(size_t)b*NN+n];
    const float mn = mnormG[(size_t)b*NN+n];
    sim[i] = __expf(beta*d/(mn*knorm + EPSF));
    sum += sim[i];
  }
  sum = blockSum1024(sum, sc);
  const float inv = 1.f/sum;
  #pragma unroll
  for (int i=0;i<4;++i){
    const int n = i*1024 + t;
    wg[n] = g*sim[i]*inv + (1.f-g)*wv[(size_t)b*NN+n];
  }
  __syncthreads();
  float wp[4]; float ps=0.f;
  #pragma unroll
  for (int i=0;i<4;++i){
    const int n = i*1024 + t;
    const float wt = s0*wg[(n+1)&(NN-1)] + s1*wg[n] + s2*wg[(n-1)&(NN-1)];
    wp[i] = __powf(wt + EPSF, gamma);
    ps += wp[i];
  }
  ps = blockSum1024(ps, sc);
  const float ip = 1.f/ps;
  #pragma unroll
  for (int i=0;i<4;++i){
    const int n = i*1024 + t;
    wv[(size_t)b*NN+n] = wp[i]*ip;
  }
}

extern "C" void kernel_launch(void* const* d_in, const int* in_sizes, int n_in,
                              void* d_out, int out_size, void* d_ws, size_t ws_size,
                              hipStream_t stream)
{
  const float* x     = (const float*)d_in[0];
  const float* mem0  = (const float*)d_in[1];
  const float* Wx    = (const float*)d_in[2];
  const float* Wr    = (const float*)d_in[3];
  const float* bC    = (const float*)d_in[4];
  const float* rWk   = (const float*)d_in[5];
  const float* rbk   = (const float*)d_in[6];
  const float* rWbeta= (const float*)d_in[7];
  const float* rWg   = (const float*)d_in[8];
  const float* rWs   = (const float*)d_in[9];
  const float* rWgam = (const float*)d_in[10];
  const float* wWk   = (const float*)d_in[11];
  const float* wbk   = (const float*)d_in[12];
  const float* wWbeta= (const float*)d_in[13];
  const float* wWg   = (const float*)d_in[14];
  const float* wWs   = (const float*)d_in[15];
  const float* wWgam = (const float*)d_in[16];
  const float* wWe   = (const float*)d_in[17];
  const float* wWa   = (const float*)d_in[18];

  float* ws = (float*)d_ws;
  size_t o = 0;
  uint4* mem    = (uint4*)(ws + o); o += (size_t)BB*NN*MM/2;  // bf16
  float* wr     = ws + o; o += (size_t)BB*NN;
  float* ww     = ws + o; o += (size_t)BB*NN;
  float* rpart  = ws + o; o += (size_t)BB*SS*MM;
  float* mnorm  = ws + o; o += (size_t)BB*NN;
  float* dotr   = ws + o; o += (size_t)BB*NN;
  float* dotw   = ws + o; o += (size_t)BB*NN;
  float* xwx    = ws + o; o += (size_t)BB*TT*HH;
  float* hG     = ws + o; o += (size_t)BB*HH;
  float* headout= ws + o; o += (size_t)BB*WC;
  float* Wall   = ws + o; o += (size_t)HH*WC;

  kCvt<<<(BB*NN*MM/8)/256, 256, 0, stream>>>(mem0, mem);
  kInit<<<(BB*NN+255)/256, 256, 0, stream>>>(wr, ww, headout);
  kPack<<<HH, 576, 0, stream>>>(rWk, wWk, wWe, wWa,
                                rWbeta, rWg, rWs, rWgam,
                                wWbeta, wWg, wWs, wWgam, Wall);
  kPre<<<(BB*TT)/16, 512, 0, stream>>>(x, Wx, bC, xwx);

  for (int t=0; t<TT; ++t){
    kA<<<dim3(SS,BB), 256, 0, stream>>>(headout, wr, ww, mem, rpart, mnorm);
    kH<<<dim3(16,16), 256, 0, stream>>>(xwx, t, Wr, rpart, hG, (float*)d_out);
    if (t < TT-1){
      kB2<<<dim3(17,16), 256, 0, stream>>>(hG, Wall, headout);
      kC<<<dim3(SS,BB), 256, 0, stream>>>(mem, headout, rbk, wbk, dotr, dotw);
      kD<<<dim3(BB,2), 1024, 0, stream>>>(dotr, dotw, mnorm, headout,
                                          rbk, wbk, wr, ww);
    }
  }
}